// Round 4
// baseline (48.904 us; speedup 1.0000x reference)
//
#include <hip/hip_runtime.h>

// BoundNoiseSampler weight: out = 4 + (1/sig2) * (1 + exp(-integral))
//   inv_C    = exp(-196/sig2) / (6*(196+sig2))   [== where(isfinite(C), 1/C, 0)]
//   integral = 0.5 * sig2 * inv_C
// Memory-bound elementwise. Residency strategy (round 4): NT LOADS stream
// sigma from HBM without polluting L3; NORMAL stores let the 128MB output
// stay dirty-resident in the 256MB Infinity Cache across graph replays, so
// steady-state HBM write traffic is absorbed (write-back, lines rewritten
// in-place each replay).

typedef float v4f __attribute__((ext_vector_type(4)));

__device__ __forceinline__ float bns_elem(float sig) {
    const float FOUR_R2 = 196.0f;              // 4*R^2, R=7
    float sig2     = sig * sig;
    float inv_sig2 = __builtin_amdgcn_rcpf(sig2);
    float e_neg    = __expf(-FOUR_R2 * inv_sig2);   // ->0 as sig->0 (matches isfinite guard)
    float inv_den  = __builtin_amdgcn_rcpf(6.0f * (FOUR_R2 + sig2));
    float inv_C    = e_neg * inv_den;
    float integral = 0.5f * sig2 * inv_C;
    float w        = __expf(-integral);
    return 4.0f + inv_sig2 * (1.0f + w);
}

__global__ void __launch_bounds__(256)
bns_kernel_vec4(const float* __restrict__ sigma, float* __restrict__ out, int nvec) {
    const v4f* in4  = reinterpret_cast<const v4f*>(sigma);
    v4f*       out4 = reinterpret_cast<v4f*>(out);
    int idx    = blockIdx.x * blockDim.x + threadIdx.x;
    int stride = gridDim.x * blockDim.x;
    for (int i = idx; i < nvec; i += stride) {
        v4f s = __builtin_nontemporal_load(&in4[i]);   // stream read, no L3 allocate
        v4f r;
        r.x = bns_elem(s.x);
        r.y = bns_elem(s.y);
        r.z = bns_elem(s.z);
        r.w = bns_elem(s.w);
        out4[i] = r;                                    // normal store: L3-resident
    }
}

__global__ void __launch_bounds__(64)
bns_kernel_tail(const float* __restrict__ sigma, float* __restrict__ out,
                int start, int n) {
    int i = start + blockIdx.x * blockDim.x + threadIdx.x;
    if (i < n) out[i] = bns_elem(sigma[i]);
}

extern "C" void kernel_launch(void* const* d_in, const int* in_sizes, int n_in,
                              void* d_out, int out_size, void* d_ws, size_t ws_size,
                              hipStream_t stream) {
    const float* sigma = (const float*)d_in[0];
    float*       out   = (float*)d_out;
    int n    = in_sizes[0];
    int nvec = n >> 2;                 // float4 elements
    int rem  = n - (nvec << 2);

    if (nvec > 0) {
        int blocks = (nvec + 255) / 256;
        if (blocks > 4096) blocks = 4096;
        bns_kernel_vec4<<<blocks, 256, 0, stream>>>(sigma, out, nvec);
    }
    if (rem > 0) {
        bns_kernel_tail<<<1, 64, 0, stream>>>(sigma, out, nvec << 2, n);
    }
}

// Round 5
// 43.655 us; speedup vs baseline: 1.1202x; 1.1202x over previous
//
#include <hip/hip_runtime.h>

// BoundNoiseSampler weight: out = 4 + (1/sig2) * (1 + exp(-integral))
//   inv_C    = exp(-196/sig2) / (6*(196+sig2))   [== where(isfinite(C), 1/C, 0)]
//   integral = 0.5 * sig2 * inv_C
// Memory-bound elementwise. Best residency split (R3): NORMAL loads
// (sigma gets partial L3 hits) + NON-TEMPORAL stores (write stream
// doesn't evict sigma from L3). R4 showed NT loads regress (48.9µs) —
// they forfeit the L3 read hits. This round: deeper MLP — 8192 blocks
// + 2x-unrolled loop issuing both loads before compute.

typedef float v4f __attribute__((ext_vector_type(4)));

__device__ __forceinline__ float bns_elem(float sig) {
    const float FOUR_R2 = 196.0f;              // 4*R^2, R=7
    float sig2     = sig * sig;
    float inv_sig2 = __builtin_amdgcn_rcpf(sig2);
    float e_neg    = __expf(-FOUR_R2 * inv_sig2);   // ->0 as sig->0 (matches isfinite guard)
    float inv_den  = __builtin_amdgcn_rcpf(6.0f * (FOUR_R2 + sig2));
    float inv_C    = e_neg * inv_den;
    float integral = 0.5f * sig2 * inv_C;
    float w        = __expf(-integral);
    return 4.0f + inv_sig2 * (1.0f + w);
}

__device__ __forceinline__ v4f bns_vec(v4f s) {
    v4f r;
    r.x = bns_elem(s.x);
    r.y = bns_elem(s.y);
    r.z = bns_elem(s.z);
    r.w = bns_elem(s.w);
    return r;
}

__global__ void __launch_bounds__(256)
bns_kernel_vec4(const float* __restrict__ sigma, float* __restrict__ out, int nvec) {
    const v4f* in4  = reinterpret_cast<const v4f*>(sigma);
    v4f*       out4 = reinterpret_cast<v4f*>(out);
    int idx    = blockIdx.x * blockDim.x + threadIdx.x;
    int stride = gridDim.x * blockDim.x;

    int i = idx;
    // 2x-unrolled main loop: issue both independent loads before compute
    for (; i + stride < nvec; i += 2 * stride) {
        v4f s0 = in4[i];
        v4f s1 = in4[i + stride];
        v4f r0 = bns_vec(s0);
        v4f r1 = bns_vec(s1);
        __builtin_nontemporal_store(r0, &out4[i]);
        __builtin_nontemporal_store(r1, &out4[i + stride]);
    }
    if (i < nvec) {
        v4f r = bns_vec(in4[i]);
        __builtin_nontemporal_store(r, &out4[i]);
    }
}

__global__ void __launch_bounds__(64)
bns_kernel_tail(const float* __restrict__ sigma, float* __restrict__ out,
                int start, int n) {
    int i = start + blockIdx.x * blockDim.x + threadIdx.x;
    if (i < n) out[i] = bns_elem(sigma[i]);
}

extern "C" void kernel_launch(void* const* d_in, const int* in_sizes, int n_in,
                              void* d_out, int out_size, void* d_ws, size_t ws_size,
                              hipStream_t stream) {
    const float* sigma = (const float*)d_in[0];
    float*       out   = (float*)d_out;
    int n    = in_sizes[0];
    int nvec = n >> 2;                 // float4 elements
    int rem  = n - (nvec << 2);

    if (nvec > 0) {
        int blocks = (nvec + 255) / 256;
        if (blocks > 8192) blocks = 8192;
        bns_kernel_vec4<<<blocks, 256, 0, stream>>>(sigma, out, nvec);
    }
    if (rem > 0) {
        bns_kernel_tail<<<1, 64, 0, stream>>>(sigma, out, nvec << 2, n);
    }
}